// Round 1
// baseline (1257.589 us; speedup 1.0000x reference)
//
#include <hip/hip_runtime.h>

#define N_NODES 100000
#define N_EDGES 1600000
#define STRN 264  // node LDS row stride in ushorts (256 + 8 pad)

typedef __attribute__((ext_vector_type(4))) float floatx4;
typedef __attribute__((ext_vector_type(8))) __bf16 bf16x8;
typedef __attribute__((ext_vector_type(8))) unsigned short ushort8;
typedef __attribute__((ext_vector_type(4))) unsigned short ushort4v;

// ---- ws layout (bytes) ----
#define WS_AGGR   0ull
#define WS_W2     51200000ull                // Wm2 bf16 [128][128]
#define WS_W3     (WS_W2 + 32768ull)         // Wm3 bf16 [128][128]
#define WS_WU1    (WS_W3 + 32768ull)         // Wu1 bf16 padded [224][256]
#define WS_WU2    (WS_WU1 + 114688ull)       // Wu2 bf16 padded [192][224]
#define WS_WU3    (WS_WU2 + 86016ull)        // Wu3 bf16 padded [128][192]

__device__ __forceinline__ unsigned short f2bf(float f) {
  unsigned u = __builtin_bit_cast(unsigned, f);
  return (unsigned short)((u + 0x7fffu + ((u >> 16) & 1u)) >> 16);  // RNE
}

__device__ __forceinline__ float leaky(float v) { return fmaxf(v, 0.01f * v); }

// ---------------- weight prep: fp32 -> bf16 (+ zero padding) ----------------
__global__ void prep_kernel(const float* __restrict__ Wm2, const float* __restrict__ Wm3,
                            const float* __restrict__ Wu1, const float* __restrict__ Wu2,
                            const float* __restrict__ Wu3,
                            unsigned short* __restrict__ o2, unsigned short* __restrict__ o3,
                            unsigned short* __restrict__ o1p, unsigned short* __restrict__ o2p,
                            unsigned short* __restrict__ o3p) {
  int i = blockIdx.x * 256 + threadIdx.x;
  if (i < 16384) {
    o2[i] = f2bf(Wm2[i]);
  } else if (i < 32768) {
    int j = i - 16384; o3[j] = f2bf(Wm3[j]);
  } else if (i < 32768 + 57344) {            // Wu1 pad [214][256] -> [224][256]
    int j = i - 32768; int n = j >> 8, k = j & 255;
    o1p[j] = (n < 214) ? f2bf(Wu1[n * 256 + k]) : (unsigned short)0;
  } else if (i < 90112 + 43008) {            // Wu2 pad [172][214] -> [192][224]
    int j = i - 90112; int n = j / 224, k = j - n * 224;
    o2p[j] = (n < 172 && k < 214) ? f2bf(Wu2[n * 214 + k]) : (unsigned short)0;
  } else if (i < 133120 + 24576) {           // Wu3 pad [128][172] -> [128][192]
    int j = i - 133120; int n = j / 192, k = j - n * 192;
    o3p[j] = (k < 172) ? f2bf(Wu3[n * 172 + k]) : (unsigned short)0;
  }
}

// ---------------- edge kernel helpers ----------------
__device__ __forceinline__ void stageW(unsigned short* __restrict__ sW,
                                       const unsigned short* __restrict__ g, int t) {
#pragma unroll
  for (int i = 0; i < 8; i++) {
    const int o = (i * 256 + t) * 8;
    *(ushort8*)(void*)&sW[o] = *(const ushort8*)(const void*)&g[o];
  }
}

template <bool FINAL>
__device__ __forceinline__ void layer_edge(unsigned short* __restrict__ sH,
                                           const unsigned short* __restrict__ sW,
                                           const float* __restrict__ bias,
                                           int wave, int lane, long blockEdge,
                                           const int* __restrict__ dst,
                                           float* __restrict__ aggr) {
  const int col = lane & 15, q = lane >> 4;
  const int eb = wave * 32;
  floatx4 acc[2][8];
#pragma unroll
  for (int i = 0; i < 2; i++)
#pragma unroll
    for (int j = 0; j < 8; j++) acc[i][j] = (floatx4){0.f, 0.f, 0.f, 0.f};

#pragma unroll
  for (int ks = 0; ks < 4; ks++) {
    const int kk = ks * 32 + q * 8;
    bf16x8 a0 = *(const bf16x8*)(const void*)&sH[(eb + col) * 128 + kk];
    bf16x8 a1 = *(const bf16x8*)(const void*)&sH[(eb + 16 + col) * 128 + kk];
#pragma unroll
    for (int nt = 0; nt < 8; nt++) {
      bf16x8 b = *(const bf16x8*)(const void*)&sW[(nt * 16 + col) * 128 + kk];
      acc[0][nt] = __builtin_amdgcn_mfma_f32_16x16x32_bf16(a0, b, acc[0][nt], 0, 0, 0);
      acc[1][nt] = __builtin_amdgcn_mfma_f32_16x16x32_bf16(a1, b, acc[1][nt], 0, 0, 0);
    }
  }

  if (!FINAL) {
#pragma unroll
    for (int nt = 0; nt < 8; nt++) {
      const int n = nt * 16 + col;
      const float bv = bias[n];
#pragma unroll
      for (int i = 0; i < 2; i++)
#pragma unroll
        for (int r = 0; r < 4; r++) {
          float v = leaky(acc[i][nt][r] + bv);
          sH[(eb + i * 16 + q * 4 + r) * 128 + n] = f2bf(v);
        }
    }
  } else {
    int dcache[2][4];
#pragma unroll
    for (int i = 0; i < 2; i++)
#pragma unroll
      for (int r = 0; r < 4; r++)
        dcache[i][r] = dst[blockEdge + eb + i * 16 + q * 4 + r];
#pragma unroll
    for (int nt = 0; nt < 8; nt++) {
      const int n = nt * 16 + col;
      const float bv = bias[n];
#pragma unroll
      for (int i = 0; i < 2; i++)
#pragma unroll
        for (int r = 0; r < 4; r++) {
          float v = acc[i][nt][r] + bv;  // msg: no activation
          unsigned d = (unsigned)dcache[i][r];
          if (d < N_NODES) atomicAdd(&aggr[(size_t)d * 128u + n], v);
        }
    }
  }
}

// ---------------- edge kernel: MLP(edge_attr) + scatter-add ----------------
__global__ __launch_bounds__(256, 2) void edge_kernel(
    const float* __restrict__ attr, const int* __restrict__ dst,
    const float* __restrict__ Wm1, const float* __restrict__ bm1,
    const unsigned short* __restrict__ W2bf, const unsigned short* __restrict__ W3bf,
    const float* __restrict__ bm2, const float* __restrict__ bm3,
    float* __restrict__ aggr) {
  __shared__ unsigned short sH[128 * 128];  // h tile [edge][k] bf16, 32KB
  __shared__ unsigned short sW[128 * 128];  // weight tile [n][k] bf16, 32KB
  const int t = threadIdx.x;
  const int wave = t >> 6, lane = t & 63;
  const long blockEdge = (long)blockIdx.x * 128;

  // stage Wm1 [128][5] + attr tile [128][5->8] as fp32 into the sW region
  float* sWm1F = (float*)(void*)sW;        // 640 floats
  float* sAttrF = sWm1F + 1024;            // 128*8 floats
  {
    const float* attrB = attr + blockEdge * 5;
    for (int i = t; i < 640; i += 256) {
      int e = i / 5, j = i - e * 5;
      sWm1F[i] = Wm1[i];
      sAttrF[e * 8 + j] = attrB[i];
    }
  }
  __syncthreads();

  // layer 1 (fp32 vector): thread -> channels {c, c+64}, 32 edges
  {
    const int c = t & 63;
    const int e0 = (t >> 6) * 32;
    const float* wa = sWm1F + c * 5;
    const float* wb = sWm1F + (c + 64) * 5;
    float wa0 = wa[0], wa1 = wa[1], wa2 = wa[2], wa3 = wa[3], wa4 = wa[4];
    float wb0 = wb[0], wb1 = wb[1], wb2 = wb[2], wb3 = wb[3], wb4 = wb[4];
    float ba = bm1[c], bb = bm1[c + 64];
#pragma unroll 4
    for (int e = 0; e < 32; e++) {
      const float* ar = sAttrF + (e0 + e) * 8;
      float4 a = *(const float4*)ar;
      float a4 = ar[4];
      float ha = fmaf(a.x, wa0, fmaf(a.y, wa1, fmaf(a.z, wa2, fmaf(a.w, wa3, fmaf(a4, wa4, ba)))));
      float hb = fmaf(a.x, wb0, fmaf(a.y, wb1, fmaf(a.z, wb2, fmaf(a.w, wb3, fmaf(a4, wb4, bb)))));
      sH[(e0 + e) * 128 + c] = f2bf(leaky(ha));
      sH[(e0 + e) * 128 + c + 64] = f2bf(leaky(hb));
    }
  }
  __syncthreads();

  stageW(sW, W2bf, t);
  __syncthreads();
  layer_edge<false>(sH, sW, bm2, wave, lane, blockEdge, nullptr, nullptr);
  __syncthreads();
  stageW(sW, W3bf, t);
  __syncthreads();
  layer_edge<true>(sH, sW, bm3, wave, lane, blockEdge, dst, aggr);
}

// ---------------- node layer (MFMA) ----------------
template <int NT, int KST, bool FINAL>
__device__ __forceinline__ void layer_node(unsigned short* __restrict__ sX,
                                           const unsigned short* __restrict__ W,
                                           const float* __restrict__ bias, int biasLim,
                                           int wave, int lane, int nodeGBase,
                                           float* __restrict__ out) {
  const int col = lane & 15, q = lane >> 4;
  floatx4 acc[NT];
#pragma unroll
  for (int i = 0; i < NT; i++) acc[i] = (floatx4){0.f, 0.f, 0.f, 0.f};
  const int rowA = wave * 16 + col;
#pragma unroll
  for (int ks = 0; ks < KST; ks++) {
    const int kk = ks * 32 + q * 8;
    bf16x8 a = *(const bf16x8*)(const void*)&sX[rowA * STRN + kk];
#pragma unroll
    for (int nt = 0; nt < NT; nt++) {
      bf16x8 b = *(const bf16x8*)(const void*)&W[(nt * 16 + col) * (KST * 32) + kk];
      acc[nt] = __builtin_amdgcn_mfma_f32_16x16x32_bf16(a, b, acc[nt], 0, 0, 0);
    }
  }
#pragma unroll
  for (int nt = 0; nt < NT; nt++) {
    const int n = nt * 16 + col;
    const float bv = (n < biasLim) ? bias[n] : 0.f;
#pragma unroll
    for (int r = 0; r < 4; r++) {
      const int row = wave * 16 + q * 4 + r;
      float v = acc[nt][r] + bv;
      if (!FINAL) {
        sX[row * STRN + n] = f2bf(leaky(v));
      } else {
        const long ng = (long)nodeGBase + row;
        if (ng < N_NODES) out[ng * 128 + n] = v;
      }
    }
  }
}

// ---------------- node kernel: LN(concat) + MLP ----------------
__global__ __launch_bounds__(256, 2) void node_kernel(
    const float* __restrict__ x, const float* __restrict__ aggr,
    const float* __restrict__ lng, const float* __restrict__ lnb,
    const unsigned short* __restrict__ Wu1p, const float* __restrict__ bu1,
    const unsigned short* __restrict__ Wu2p, const float* __restrict__ bu2,
    const unsigned short* __restrict__ Wu3p, const float* __restrict__ bu3,
    float* __restrict__ out) {
  __shared__ unsigned short sX[64 * STRN];  // [node][c] bf16, padded stride
  __shared__ float sG[256], sB[256];
  const int t = threadIdx.x;
  const int wave = t >> 6, lane = t & 63;
  sG[t] = lng[t];
  sB[t] = lnb[t];

  // LayerNorm over cat=[x,aggr] (fp32). 4 threads per node.
  const int nl = t >> 2;
  const int part = t & 3;
  const long nodeG = (long)blockIdx.x * 64 + nl;
  const bool valid = nodeG < N_NODES;
  const float* src = (part < 2) ? (x + nodeG * 128 + part * 64)
                                : (aggr + nodeG * 128 + (part - 2) * 64);
  float s = 0.f, ss = 0.f;
  if (valid) {
#pragma unroll
    for (int i = 0; i < 16; i++) {
      float4 a = *(const float4*)(src + i * 4);
      s += a.x + a.y + a.z + a.w;
      ss += a.x * a.x + a.y * a.y + a.z * a.z + a.w * a.w;
    }
  }
  s += __shfl_xor(s, 1); s += __shfl_xor(s, 2);
  ss += __shfl_xor(ss, 1); ss += __shfl_xor(ss, 2);
  const float mean = s * (1.f / 256.f);
  const float var = ss * (1.f / 256.f) - mean * mean;
  const float rstd = rsqrtf(var + 1e-5f);
  __syncthreads();  // sG/sB visible
  const int cb = part * 64;
#pragma unroll
  for (int i = 0; i < 16; i++) {
    float4 a = valid ? *(const float4*)(src + i * 4) : make_float4(0.f, 0.f, 0.f, 0.f);
    int c = cb + i * 4;
    ushort4v p;
    p[0] = f2bf((a.x - mean) * rstd * sG[c + 0] + sB[c + 0]);
    p[1] = f2bf((a.y - mean) * rstd * sG[c + 1] + sB[c + 1]);
    p[2] = f2bf((a.z - mean) * rstd * sG[c + 2] + sB[c + 2]);
    p[3] = f2bf((a.w - mean) * rstd * sG[c + 3] + sB[c + 3]);
    *(ushort4v*)(void*)&sX[nl * STRN + c] = p;
  }
  __syncthreads();

  const int nodeGBase = blockIdx.x * 64;
  layer_node<14, 8, false>(sX, Wu1p, bu1, 214, wave, lane, nodeGBase, nullptr);
  __syncthreads();
  layer_node<12, 7, false>(sX, Wu2p, bu2, 172, wave, lane, nodeGBase, nullptr);
  __syncthreads();
  layer_node<8, 6, true>(sX, Wu3p, bu3, 128, wave, lane, nodeGBase, out);
}

// ---------------- launch ----------------
extern "C" void kernel_launch(void* const* d_in, const int* in_sizes, int n_in,
                              void* d_out, int out_size, void* d_ws, size_t ws_size,
                              hipStream_t stream) {
  const float* x    = (const float*)d_in[0];
  const int*   eidx = (const int*)d_in[1];
  const float* attr = (const float*)d_in[2];
  const float* Wm1  = (const float*)d_in[3];
  const float* bm1  = (const float*)d_in[4];
  const float* Wm2  = (const float*)d_in[5];
  const float* bm2  = (const float*)d_in[6];
  const float* Wm3  = (const float*)d_in[7];
  const float* bm3  = (const float*)d_in[8];
  const float* lng  = (const float*)d_in[9];
  const float* lnb  = (const float*)d_in[10];
  const float* Wu1  = (const float*)d_in[11];
  const float* bu1  = (const float*)d_in[12];
  const float* Wu2  = (const float*)d_in[13];
  const float* bu2  = (const float*)d_in[14];
  const float* Wu3  = (const float*)d_in[15];
  const float* bu3  = (const float*)d_in[16];
  float* out = (float*)d_out;

  char* ws = (char*)d_ws;
  float* aggr = (float*)(ws + WS_AGGR);
  unsigned short* W2bf = (unsigned short*)(ws + WS_W2);
  unsigned short* W3bf = (unsigned short*)(ws + WS_W3);
  unsigned short* Wu1p = (unsigned short*)(ws + WS_WU1);
  unsigned short* Wu2p = (unsigned short*)(ws + WS_WU2);
  unsigned short* Wu3p = (unsigned short*)(ws + WS_WU3);

  hipMemsetAsync(aggr, 0, (size_t)N_NODES * 128 * sizeof(float), stream);
  prep_kernel<<<616, 256, 0, stream>>>(Wm2, Wm3, Wu1, Wu2, Wu3, W2bf, W3bf, Wu1p, Wu2p, Wu3p);

  const int* dst = eidx + N_EDGES;  // edge_index[1]
  edge_kernel<<<N_EDGES / 128, 256, 0, stream>>>(attr, dst, Wm1, bm1, W2bf, W3bf, bm2, bm3, aggr);
  node_kernel<<<(N_NODES + 63) / 64, 256, 0, stream>>>(x, aggr, lng, lnb, Wu1p, bu1, Wu2p, bu2,
                                                       Wu3p, bu3, out);
}

// Round 2
// 943.055 us; speedup vs baseline: 1.3335x; 1.3335x over previous
//
#include <hip/hip_runtime.h>

#define N_NODES 100000
#define N_EDGES 1600000
#define STRN 264        // node LDS row stride in ushorts (256 + 8 pad)
#define NBLK_SCAN 391   // ceil(100000/256)

typedef __attribute__((ext_vector_type(4))) float floatx4;
typedef __attribute__((ext_vector_type(8))) __bf16 bf16x8;
typedef __attribute__((ext_vector_type(8))) unsigned short ushort8;
typedef __attribute__((ext_vector_type(4))) unsigned short ushort4v;

// ---- ws layout (bytes) ----
#define WS_AGGR   0ull                        // 51,200,000  fp32 [N][128]
#define WS_COUNTS 51200000ull                 // 400,384     int[100096]
#define WS_OFFS   51600384ull                 // 400,384
#define WS_PART   52000768ull                 // 2,048       int[512]
#define WS_PERM   52002816ull                 // 6,400,000   int[E]
#define WS_DSTS   58402816ull                 // 6,400,000   int[E]
#define WS_W2     64802816ull                 // Wm2 bf16 [128][128]
#define WS_W3     (WS_W2 + 32768ull)
#define WS_WU1    (WS_W3 + 32768ull)          // Wu1 bf16 padded [224][256]
#define WS_WU2    (WS_WU1 + 114688ull)        // Wu2 bf16 padded [192][224]
#define WS_WU3    (WS_WU2 + 86016ull)         // Wu3 bf16 padded [128][192]

__device__ __forceinline__ unsigned short f2bf(float f) {
  unsigned u = __builtin_bit_cast(unsigned, f);
  return (unsigned short)((u + 0x7fffu + ((u >> 16) & 1u)) >> 16);  // RNE
}

__device__ __forceinline__ float leaky(float v) { return fmaxf(v, 0.01f * v); }

// XOR-swizzled ushort index into a [128 rows][128 ch] bf16 LDS tile:
// chunk (8-ch group) index XOR row&7 -> 8-lane b128 groups hit 8 distinct bank quads.
__device__ __forceinline__ int swz(int row, int ch) {
  return row * 128 + (ch ^ ((row & 7) << 3));
}

// ---------------- weight prep: fp32 -> bf16 (+ zero padding) ----------------
__global__ void prep_kernel(const float* __restrict__ Wm2, const float* __restrict__ Wm3,
                            const float* __restrict__ Wu1, const float* __restrict__ Wu2,
                            const float* __restrict__ Wu3,
                            unsigned short* __restrict__ o2, unsigned short* __restrict__ o3,
                            unsigned short* __restrict__ o1p, unsigned short* __restrict__ o2p,
                            unsigned short* __restrict__ o3p) {
  int i = blockIdx.x * 256 + threadIdx.x;
  if (i < 16384) {
    o2[i] = f2bf(Wm2[i]);
  } else if (i < 32768) {
    int j = i - 16384; o3[j] = f2bf(Wm3[j]);
  } else if (i < 32768 + 57344) {            // Wu1 pad [214][256] -> [224][256]
    int j = i - 32768; int n = j >> 8, k = j & 255;
    o1p[j] = (n < 214) ? f2bf(Wu1[n * 256 + k]) : (unsigned short)0;
  } else if (i < 90112 + 43008) {            // Wu2 pad [172][214] -> [192][224]
    int j = i - 90112; int n = j / 224, k = j - n * 224;
    o2p[j] = (n < 172 && k < 214) ? f2bf(Wu2[n * 214 + k]) : (unsigned short)0;
  } else if (i < 133120 + 24576) {           // Wu3 pad [128][172] -> [128][192]
    int j = i - 133120; int n = j / 192, k = j - n * 192;
    o3p[j] = (k < 172) ? f2bf(Wu3[n * 172 + k]) : (unsigned short)0;
  }
}

// ---------------- counting sort of edges by dst ----------------
__global__ void hist_kernel(const int* __restrict__ dst, int* __restrict__ counts) {
  int e = blockIdx.x * 256 + threadIdx.x;
  if (e < N_EDGES) atomicAdd(&counts[dst[e]], 1);
}

__global__ void scanA_kernel(const int* __restrict__ counts, int* __restrict__ offs,
                             int* __restrict__ partials) {
  __shared__ int tmp[256];
  const int t = threadIdx.x;
  const int i = blockIdx.x * 256 + t;
  int v = (i < N_NODES) ? counts[i] : 0;
  tmp[t] = v;
  __syncthreads();
  for (int off = 1; off < 256; off <<= 1) {
    int a = (t >= off) ? tmp[t - off] : 0;
    __syncthreads();
    tmp[t] += a;
    __syncthreads();
  }
  if (i < N_NODES) offs[i] = tmp[t] - v;  // exclusive
  if (t == 255) partials[blockIdx.x] = tmp[255];
}

__global__ void scanB_kernel(int* __restrict__ partials) {
  __shared__ int tmp[512];
  const int t = threadIdx.x;
  int v = (t < NBLK_SCAN) ? partials[t] : 0;
  tmp[t] = v;
  __syncthreads();
  for (int off = 1; off < 512; off <<= 1) {
    int a = (t >= off) ? tmp[t - off] : 0;
    __syncthreads();
    tmp[t] += a;
    __syncthreads();
  }
  if (t < NBLK_SCAN) partials[t] = tmp[t] - v;  // exclusive
}

__global__ void scanC_kernel(int* __restrict__ offs, const int* __restrict__ partials) {
  int i = blockIdx.x * 256 + threadIdx.x;
  if (i < N_NODES) offs[i] += partials[blockIdx.x];
}

__global__ void scatter_kernel(const int* __restrict__ dst, int* __restrict__ offs,
                               int* __restrict__ perm, int* __restrict__ dsts) {
  int e = blockIdx.x * 256 + threadIdx.x;
  if (e < N_EDGES) {
    int d = dst[e];
    int p = atomicAdd(&offs[d], 1);
    perm[p] = e;
    dsts[p] = d;
  }
}

// ---------------- edge kernel: MLP(edge_attr) on dst-sorted edges + segmented scatter ----
__global__ __launch_bounds__(256, 2) void edge_kernel(
    const float* __restrict__ attr, const int* __restrict__ perm,
    const int* __restrict__ dsts,
    const float* __restrict__ Wm1, const float* __restrict__ bm1,
    const unsigned short* __restrict__ W2bf, const float* __restrict__ bm2,
    const unsigned short* __restrict__ W3bf, const float* __restrict__ bm3,
    float* __restrict__ aggr) {
  __shared__ float4 smemv[4096];  // 64 KB, multi-purpose
  unsigned short* sH = (unsigned short*)smemv;      // 32 KB: h tile [edge][k] bf16, swizzled
  unsigned short* sW = sH + 16384;                  // 32 KB: weight tile [n][k] bf16, swizzled
  float* sMsgF = (float*)smemv;                     // 64 KB: msg fp32 [128][128] (post-MFMA)
  int* sPerm = (int*)sH;                            // phase-A scratch (512 B)
  float* sWm1F = (float*)(void*)sW;                 // 640 floats
  float* sAttrF = sWm1F + 1024;                     // 128*8 floats

  const int t = threadIdx.x;
  const int wave = t >> 6, lane = t & 63;
  const int col = lane & 15, q = lane >> 4;
  const int eb = wave * 32;
  const long blockEdge = (long)blockIdx.x * 128;

  // ---- phase A: stage perm slice + Wm1 ----
  if (t < 128) sPerm[t] = perm[blockEdge + t];
  for (int i = t; i < 640; i += 256) sWm1F[i] = Wm1[i];
  __syncthreads();

  // ---- phase B: gather attr rows via perm ----
  for (int i = t; i < 640; i += 256) {
    int e = i / 5, j = i - e * 5;
    sAttrF[e * 8 + j] = attr[(size_t)sPerm[e] * 5 + j];
  }
  __syncthreads();

  // ---- layer 1 (fp32 vector): thread -> channels {c, c+64}, 32 edges ----
  {
    const int c = t & 63;
    const int e0 = (t >> 6) * 32;
    const float* wa = sWm1F + c * 5;
    const float* wb = sWm1F + (c + 64) * 5;
    float wa0 = wa[0], wa1 = wa[1], wa2 = wa[2], wa3 = wa[3], wa4 = wa[4];
    float wb0 = wb[0], wb1 = wb[1], wb2 = wb[2], wb3 = wb[3], wb4 = wb[4];
    float ba = bm1[c], bb = bm1[c + 64];
#pragma unroll 4
    for (int e = 0; e < 32; e++) {
      const float* ar = sAttrF + (e0 + e) * 8;
      float4 a = *(const float4*)ar;
      float a4 = ar[4];
      float ha = fmaf(a.x, wa0, fmaf(a.y, wa1, fmaf(a.z, wa2, fmaf(a.w, wa3, fmaf(a4, wa4, ba)))));
      float hb = fmaf(a.x, wb0, fmaf(a.y, wb1, fmaf(a.z, wb2, fmaf(a.w, wb3, fmaf(a4, wb4, bb)))));
      sH[swz(e0 + e, c)] = f2bf(leaky(ha));
      sH[swz(e0 + e, c + 64)] = f2bf(leaky(hb));
    }
  }
  __syncthreads();

  // ---- layer 2: stage W2, MFMA, epilogue back to sH ----
  {
#pragma unroll
    for (int i = 0; i < 8; i++) {
      const int o = (i * 256 + t) * 8;
      *(ushort8*)(void*)&sW[swz(o >> 7, o & 127)] = *(const ushort8*)(const void*)&W2bf[o];
    }
  }
  __syncthreads();
  {
    floatx4 acc[2][8];
#pragma unroll
    for (int i = 0; i < 2; i++)
#pragma unroll
      for (int j = 0; j < 8; j++) acc[i][j] = (floatx4){0.f, 0.f, 0.f, 0.f};
#pragma unroll
    for (int ks = 0; ks < 4; ks++) {
      const int kk = ks * 32 + q * 8;
      bf16x8 a0 = *(const bf16x8*)(const void*)&sH[swz(eb + col, kk)];
      bf16x8 a1 = *(const bf16x8*)(const void*)&sH[swz(eb + 16 + col, kk)];
#pragma unroll
      for (int nt = 0; nt < 8; nt++) {
        bf16x8 b = *(const bf16x8*)(const void*)&sW[swz(nt * 16 + col, kk)];
        acc[0][nt] = __builtin_amdgcn_mfma_f32_16x16x32_bf16(a0, b, acc[0][nt], 0, 0, 0);
        acc[1][nt] = __builtin_amdgcn_mfma_f32_16x16x32_bf16(a1, b, acc[1][nt], 0, 0, 0);
      }
    }
#pragma unroll
    for (int nt = 0; nt < 8; nt++) {
      const int n = nt * 16 + col;
      const float bv = bm2[n];
#pragma unroll
      for (int i = 0; i < 2; i++)
#pragma unroll
        for (int r = 0; r < 4; r++)
          sH[swz(eb + i * 16 + q * 4 + r, n)] = f2bf(leaky(acc[i][nt][r] + bv));
    }
  }
  __syncthreads();

  // ---- layer 3: stage W3, MFMA ----
  {
#pragma unroll
    for (int i = 0; i < 8; i++) {
      const int o = (i * 256 + t) * 8;
      *(ushort8*)(void*)&sW[swz(o >> 7, o & 127)] = *(const ushort8*)(const void*)&W3bf[o];
    }
  }
  __syncthreads();
  floatx4 acc[2][8];
#pragma unroll
  for (int i = 0; i < 2; i++)
#pragma unroll
    for (int j = 0; j < 8; j++) acc[i][j] = (floatx4){0.f, 0.f, 0.f, 0.f};
#pragma unroll
  for (int ks = 0; ks < 4; ks++) {
    const int kk = ks * 32 + q * 8;
    bf16x8 a0 = *(const bf16x8*)(const void*)&sH[swz(eb + col, kk)];
    bf16x8 a1 = *(const bf16x8*)(const void*)&sH[swz(eb + 16 + col, kk)];
#pragma unroll
    for (int nt = 0; nt < 8; nt++) {
      bf16x8 b = *(const bf16x8*)(const void*)&sW[swz(nt * 16 + col, kk)];
      acc[0][nt] = __builtin_amdgcn_mfma_f32_16x16x32_bf16(a0, b, acc[0][nt], 0, 0, 0);
      acc[1][nt] = __builtin_amdgcn_mfma_f32_16x16x32_bf16(a1, b, acc[1][nt], 0, 0, 0);
    }
  }
  __syncthreads();  // all sH/sW reads done; smem becomes sMsgF

  // ---- write msg fp32 to LDS (swizzled: ch ^ ((row>>2)&3)*8 keeps banks 2-way) ----
#pragma unroll
  for (int nt = 0; nt < 8; nt++) {
    const int n = nt * 16 + col;
    const float bv = bm3[n];
#pragma unroll
    for (int i = 0; i < 2; i++)
#pragma unroll
      for (int r = 0; r < 4; r++) {
        const int row = eb + i * 16 + q * 4 + r;
        sMsgF[row * 128 + (n ^ (((row >> 2) & 3) << 3))] = acc[i][nt][r] + bv;
      }
  }
  __syncthreads();

  // ---- segmented walk: one atomic per (distinct dst, channel) per block ----
  {
    const int cc = (t & 63) + ((wave & 1) << 6);  // channel
    const int half = wave >> 1;                   // edge half [0,64) / [64,128)
    const int e0w = half * 64;
    int dAll = dsts[blockEdge + e0w + (t & 63)];  // lane l holds dst of edge e0w+l
    float accv = 0.f;
    int dprev = __shfl(dAll, 0);
#pragma unroll 8
    for (int e = 0; e < 64; e++) {
      int d = __shfl(dAll, e);  // wave-uniform
      float v = sMsgF[(e0w + e) * 128 + (cc ^ (((e >> 2) & 3) << 3))];
      if (d != dprev) {
        atomicAdd(&aggr[(size_t)dprev * 128 + cc], accv);
        accv = 0.f;
        dprev = d;
      }
      accv += v;
    }
    atomicAdd(&aggr[(size_t)dprev * 128 + cc], accv);
  }
}

// ---------------- node layer (MFMA) ----------------
template <int NT, int KST, bool FINAL>
__device__ __forceinline__ void layer_node(unsigned short* __restrict__ sX,
                                           const unsigned short* __restrict__ W,
                                           const float* __restrict__ bias, int biasLim,
                                           int wave, int lane, int nodeGBase,
                                           float* __restrict__ out) {
  const int col = lane & 15, q = lane >> 4;
  floatx4 acc[NT];
#pragma unroll
  for (int i = 0; i < NT; i++) acc[i] = (floatx4){0.f, 0.f, 0.f, 0.f};
  const int rowA = wave * 16 + col;
#pragma unroll
  for (int ks = 0; ks < KST; ks++) {
    const int kk = ks * 32 + q * 8;
    bf16x8 a = *(const bf16x8*)(const void*)&sX[rowA * STRN + kk];
#pragma unroll
    for (int nt = 0; nt < NT; nt++) {
      bf16x8 b = *(const bf16x8*)(const void*)&W[(nt * 16 + col) * (KST * 32) + kk];
      acc[nt] = __builtin_amdgcn_mfma_f32_16x16x32_bf16(a, b, acc[nt], 0, 0, 0);
    }
  }
#pragma unroll
  for (int nt = 0; nt < NT; nt++) {
    const int n = nt * 16 + col;
    const float bv = (n < biasLim) ? bias[n] : 0.f;
#pragma unroll
    for (int r = 0; r < 4; r++) {
      const int row = wave * 16 + q * 4 + r;
      float v = acc[nt][r] + bv;
      if (!FINAL) {
        sX[row * STRN + n] = f2bf(leaky(v));
      } else {
        const long ng = (long)nodeGBase + row;
        if (ng < N_NODES) out[ng * 128 + n] = v;
      }
    }
  }
}

// ---------------- node kernel: LN(concat) + MLP ----------------
__global__ __launch_bounds__(256, 2) void node_kernel(
    const float* __restrict__ x, const float* __restrict__ aggr,
    const float* __restrict__ lng, const float* __restrict__ lnb,
    const unsigned short* __restrict__ Wu1p, const float* __restrict__ bu1,
    const unsigned short* __restrict__ Wu2p, const float* __restrict__ bu2,
    const unsigned short* __restrict__ Wu3p, const float* __restrict__ bu3,
    float* __restrict__ out) {
  __shared__ unsigned short sX[64 * STRN];  // [node][c] bf16, padded stride
  __shared__ float sG[256], sB[256];
  const int t = threadIdx.x;
  const int wave = t >> 6, lane = t & 63;
  sG[t] = lng[t];
  sB[t] = lnb[t];

  // LayerNorm over cat=[x,aggr] (fp32). 4 threads per node.
  const int nl = t >> 2;
  const int part = t & 3;
  const long nodeG = (long)blockIdx.x * 64 + nl;
  const bool valid = nodeG < N_NODES;
  const float* src = (part < 2) ? (x + nodeG * 128 + part * 64)
                                : (aggr + nodeG * 128 + (part - 2) * 64);
  float s = 0.f, ss = 0.f;
  if (valid) {
#pragma unroll
    for (int i = 0; i < 16; i++) {
      float4 a = *(const float4*)(src + i * 4);
      s += a.x + a.y + a.z + a.w;
      ss += a.x * a.x + a.y * a.y + a.z * a.z + a.w * a.w;
    }
  }
  s += __shfl_xor(s, 1); s += __shfl_xor(s, 2);
  ss += __shfl_xor(ss, 1); ss += __shfl_xor(ss, 2);
  const float mean = s * (1.f / 256.f);
  const float var = ss * (1.f / 256.f) - mean * mean;
  const float rstd = rsqrtf(var + 1e-5f);
  __syncthreads();  // sG/sB visible
  const int cb = part * 64;
#pragma unroll
  for (int i = 0; i < 16; i++) {
    float4 a = valid ? *(const float4*)(src + i * 4) : make_float4(0.f, 0.f, 0.f, 0.f);
    int c = cb + i * 4;
    ushort4v p;
    p[0] = f2bf((a.x - mean) * rstd * sG[c + 0] + sB[c + 0]);
    p[1] = f2bf((a.y - mean) * rstd * sG[c + 1] + sB[c + 1]);
    p[2] = f2bf((a.z - mean) * rstd * sG[c + 2] + sB[c + 2]);
    p[3] = f2bf((a.w - mean) * rstd * sG[c + 3] + sB[c + 3]);
    *(ushort4v*)(void*)&sX[nl * STRN + c] = p;
  }
  __syncthreads();

  const int nodeGBase = blockIdx.x * 64;
  layer_node<14, 8, false>(sX, Wu1p, bu1, 214, wave, lane, nodeGBase, nullptr);
  __syncthreads();
  layer_node<12, 7, false>(sX, Wu2p, bu2, 172, wave, lane, nodeGBase, nullptr);
  __syncthreads();
  layer_node<8, 6, true>(sX, Wu3p, bu3, 128, wave, lane, nodeGBase, out);
}

// ---------------- launch ----------------
extern "C" void kernel_launch(void* const* d_in, const int* in_sizes, int n_in,
                              void* d_out, int out_size, void* d_ws, size_t ws_size,
                              hipStream_t stream) {
  const float* x    = (const float*)d_in[0];
  const int*   eidx = (const int*)d_in[1];
  const float* attr = (const float*)d_in[2];
  const float* Wm1  = (const float*)d_in[3];
  const float* bm1  = (const float*)d_in[4];
  const float* Wm2  = (const float*)d_in[5];
  const float* bm2  = (const float*)d_in[6];
  const float* Wm3  = (const float*)d_in[7];
  const float* bm3  = (const float*)d_in[8];
  const float* lng  = (const float*)d_in[9];
  const float* lnb  = (const float*)d_in[10];
  const float* Wu1  = (const float*)d_in[11];
  const float* bu1  = (const float*)d_in[12];
  const float* Wu2  = (const float*)d_in[13];
  const float* bu2  = (const float*)d_in[14];
  const float* Wu3  = (const float*)d_in[15];
  const float* bu3  = (const float*)d_in[16];
  float* out = (float*)d_out;

  char* ws = (char*)d_ws;
  float* aggr = (float*)(ws + WS_AGGR);
  int* counts = (int*)(ws + WS_COUNTS);
  int* offs   = (int*)(ws + WS_OFFS);
  int* parts  = (int*)(ws + WS_PART);
  int* perm   = (int*)(ws + WS_PERM);
  int* dsts   = (int*)(ws + WS_DSTS);
  unsigned short* W2bf = (unsigned short*)(ws + WS_W2);
  unsigned short* W3bf = (unsigned short*)(ws + WS_W3);
  unsigned short* Wu1p = (unsigned short*)(ws + WS_WU1);
  unsigned short* Wu2p = (unsigned short*)(ws + WS_WU2);
  unsigned short* Wu3p = (unsigned short*)(ws + WS_WU3);

  const int* dst = eidx + N_EDGES;  // edge_index[1]

  // counting sort of edges by dst
  hipMemsetAsync(counts, 0, 400384, stream);
  hist_kernel<<<6250, 256, 0, stream>>>(dst, counts);
  scanA_kernel<<<NBLK_SCAN, 256, 0, stream>>>(counts, offs, parts);
  scanB_kernel<<<1, 512, 0, stream>>>(parts);
  scanC_kernel<<<NBLK_SCAN, 256, 0, stream>>>(offs, parts);
  scatter_kernel<<<6250, 256, 0, stream>>>(dst, offs, perm, dsts);

  hipMemsetAsync(aggr, 0, (size_t)N_NODES * 128 * sizeof(float), stream);
  prep_kernel<<<616, 256, 0, stream>>>(Wm2, Wm3, Wu1, Wu2, Wu3, W2bf, W3bf, Wu1p, Wu2p, Wu3p);

  edge_kernel<<<N_EDGES / 128, 256, 0, stream>>>(attr, perm, dsts, Wm1, bm1, W2bf, bm2, W3bf,
                                                 bm3, aggr);
  node_kernel<<<(N_NODES + 63) / 64, 256, 0, stream>>>(x, aggr, lng, lnb, Wu1p, bu1, Wu2p, bu2,
                                                       Wu3p, bu3, out);
}